// Round 4
// baseline (476.030 us; speedup 1.0000x reference)
//
#include <hip/hip_runtime.h>
#include <hip/hip_bf16.h>

#define NB 32
#define NS 2048
#define DIM 1024
#define NM (NB*NS)   // 65536 rows

typedef __attribute__((ext_vector_type(8))) short short8;
typedef __attribute__((ext_vector_type(4))) float f32x4;
typedef unsigned short us16;
typedef unsigned int   u32;
typedef __attribute__((address_space(3))) void lds_void;
typedef __attribute__((address_space(1))) void glb_void;

__device__ __forceinline__ void gload16(const void* g, void* l){
  __builtin_amdgcn_global_load_lds((const glb_void*)g, (lds_void*)l, 16, 0, 0);
}

__device__ __forceinline__ float fast_tanh(float x){
  float e = __builtin_exp2f(x * 2.8853900817779268f); // e^{2x}
  return 1.0f - 2.0f/(e + 1.0f);
}

// split f32 into bf16 hi (truncated) + bf16 lo (residual); rep error ~2^-16 rel
__device__ __forceinline__ void split_bf16(float x, short &hi, short &lo){
  u32 u = __float_as_uint(x);
  float hf = __uint_as_float(u & 0xFFFF0000u);
  hi = (short)(u >> 16);
  lo = (short)(__float_as_uint(x - hf) >> 16);
}

// ---------------- Wb -> pre-swizzled hi|lo image for global_load_lds ----------
// image = [kt(32)][ct128(8)][16384B tile]; within a tile, byte b holds element
// j = ((b&127) ^ ((r&7)<<4))>>1 of row r=b>>7  (j<32: hi(wb), j>=32: lo(wb))
__global__ void k_split_wb(const float* __restrict__ wb, char* __restrict__ img){
  const int tid = blockIdx.x*256 + threadIdx.x;       // 262144 threads, 16B each
  const int tt = tid >> 10;                           // tile index
  const int kt = tt >> 3, ct = tt & 7;
  const int b14 = (tid & 1023) * 16;                  // tile-local byte offset
  const int r  = b14 >> 7, c = b14 & 127;
  const int j0 = (c ^ ((r & 7) << 4)) >> 1;           // multiple of 8
  const float* src = wb + (size_t)(ct*128 + r)*DIM + kt*32 + (j0 & 31);
  float4 v0 = *(const float4*)src;
  float4 v1 = *(const float4*)(src + 4);
  float fv[8] = {v0.x,v0.y,v0.z,v0.w,v1.x,v1.y,v1.z,v1.w};
  short8 out;
  const bool lohalf = (j0 >= 32);
  #pragma unroll
  for(int j=0;j<8;j++){
    short hi,lo; split_bf16(fv[j],hi,lo);
    out[j] = lohalf ? lo : hi;
  }
  *(short8*)(img + (size_t)tid*16) = out;
}

// ---------------- a = k @ Wa^T ----------------
__global__ void k_compute_a(const float* __restrict__ kin,
                            const float* __restrict__ wa,
                            float* __restrict__ avec){
  __shared__ float4 kl[256];
  const int b = blockIdx.x >> 2, oc = blockIdx.x & 3;
  const int t = threadIdx.x;
  kl[t] = *(const float4*)(kin + b*DIM + t*4);
  __syncthreads();
  const int o = oc*256 + t;
  const float4* wrow = (const float4*)(wa + (size_t)o*DIM);
  float acc = 0.f;
  for(int i=0;i<256;i++){
    float4 wv = wrow[i]; float4 kk = kl[i];
    acc += wv.x*kk.x + wv.y*kk.y + wv.z*kk.z + wv.w*kk.w;
  }
  avec[b*DIM + o] = acc;
}

// split 16 f32 (ar0..ar3) -> hi/lo bf16, store swizzled to Abuf at row sr
#define SPLIT_STORE_A(AR0,AR1,AR2,AR3)                                          \
  {                                                                             \
    float fv[16];                                                               \
    *(float4*)(fv+0)=AR0; *(float4*)(fv+4)=AR1;                                 \
    *(float4*)(fv+8)=AR2; *(float4*)(fv+12)=AR3;                                \
    short8 h0,h1,l0,l1;                                                         \
    _Pragma("unroll")                                                           \
    for(int j=0;j<8;j++){ short a,b; split_bf16(fv[j],a,b);   h0[j]=a; l0[j]=b; }\
    _Pragma("unroll")                                                           \
    for(int j=0;j<8;j++){ short a,b; split_bf16(fv[8+j],a,b); h1[j]=a; l1[j]=b; }\
    const int swz = (sr & 7) << 4;                                              \
    char* abase = (char*)&Abuf[0][0] + sr*128;                                  \
    *(short8*)(abase + ((sh*32      ) ^ swz)) = h0;                             \
    *(short8*)(abase + ((sh*32 + 16 ) ^ swz)) = h1;                             \
    *(short8*)(abase + ((64 + sh*32     ) ^ swz)) = l0;                         \
    *(short8*)(abase + ((64 + sh*32 + 16) ^ swz)) = l1;                         \
  }

// ---------------- main GEMM (128x256) — stage-under-MFMA schedule ----------
__global__ __launch_bounds__(256,2)
void k_gemm_scores(const float* __restrict__ xs,
                   const char* __restrict__ wbimg,
                   const float* __restrict__ avec,
                   const float* __restrict__ energy,
                   float* __restrict__ partial){
  __shared__ us16 Abuf[128][64];      // hi cols 0..31 | lo 32..63, XOR-swizzled
  __shared__ us16 Bbuf[2][256][64];   // double-buffered, global_load_lds target

  const int h  = blockIdx.x;                  // 2048 blocks
  const int rt = (h & 7) + 8*(h >> 5);        // same-rt blocks on same XCD
  const int cb = (h >> 3) & 3;                // 256-col tile index
  const int t  = threadIdx.x;
  const int w  = t >> 6, lane = t & 63;
  const int wr = w >> 1, wc = w & 1;          // wave tile: 64 rows x 128 cols
  const int lm = lane & 15, lk = lane >> 4;
  const int sr = t >> 1, sh = t & 1;

  const float* ap   = xs + (size_t)(rt*128 + sr)*DIM + sh*16;
  const char*  bsrc = wbimg + cb*32768;       // + kt*131072 per K-step

  // loop-invariant read addresses
  const char* ab_rd  = (const char*)&Abuf[0][0]    + (wr*64  + lm)*128;
  const char* bb0_rd = (const char*)&Bbuf[0][0][0] + (wc*128 + lm)*128;
  const char* bb1_rd = (const char*)&Bbuf[1][0][0] + (wc*128 + lm)*128;
  const int off_h = (lk*16) ^ ((lm&7)<<4);
  const int off_l = (64 + lk*16) ^ ((lm&7)<<4);

  f32x4 acc[4][8];
  #pragma unroll
  for(int m=0;m<4;m++)
    #pragma unroll
    for(int n=0;n<8;n++) acc[m][n] = (f32x4){0.f,0.f,0.f,0.f};

  // ---- prologue ----
  float4 ar0 = *(const float4*)(ap+0),  ar1 = *(const float4*)(ap+4);
  float4 ar2 = *(const float4*)(ap+8),  ar3 = *(const float4*)(ap+12);
  {                                     // issue B(0)->buf0, B(1)->buf1
    const char* gs0 = bsrc + w*8192 + lane*16;
    char* ld0 = (char*)&Bbuf[0][0][0] + w*8192;
    #pragma unroll
    for(int cch=0; cch<8; cch++) gload16(gs0 + cch*1024, ld0 + cch*1024);
    const char* gs1 = bsrc + 131072 + w*8192 + lane*16;
    char* ld1 = (char*)&Bbuf[1][0][0] + w*8192;
    #pragma unroll
    for(int cch=0; cch<8; cch++) gload16(gs1 + cch*1024, ld1 + cch*1024);
  }
  SPLIT_STORE_A(ar0, ar1, ar2, ar3);    // A(0) -> LDS
  {
    const float* a2 = ap + 32;          // load A(1) -> regs
    ar0 = *(const float4*)(a2+0);  ar1 = *(const float4*)(a2+4);
    ar2 = *(const float4*)(a2+8);  ar3 = *(const float4*)(a2+12);
  }
  asm volatile("s_waitcnt vmcnt(12) lgkmcnt(0)" ::: "memory");  // B(0) + A-writes done
  __builtin_amdgcn_sched_barrier(0);
  __builtin_amdgcn_s_barrier();

  // ---- main loop ----
  for(int kt=0; kt<32; kt++){
    // read ALL frags for kt into regs (before barrier: buffers get overwritten after)
    const char* bb = (kt & 1) ? bb1_rd : bb0_rd;
    short8 fah[4], fal[4], fbh[8], fbl[8];
    #pragma unroll
    for(int m=0;m<4;m++){
      fah[m] = *(const short8*)(ab_rd + m*2048 + off_h);
      fal[m] = *(const short8*)(ab_rd + m*2048 + off_l);
    }
    #pragma unroll
    for(int n=0;n<8;n++){
      fbh[n] = *(const short8*)(bb + n*2048 + off_h);
      fbl[n] = *(const short8*)(bb + n*2048 + off_l);
    }
    asm volatile("s_waitcnt lgkmcnt(0)" ::: "memory");
    __builtin_amdgcn_sched_barrier(0);
    __builtin_amdgcn_s_barrier();       // Abuf + Bbuf[kt&1] now free

    // ---- staging for future iters, scheduled under the MFMA cluster ----
    if(kt < 30){                        // issue B(kt+2) -> Bbuf[kt&1]
      const char* gs = bsrc + (kt+2)*131072 + w*8192 + lane*16;
      char* ld = (char*)&Bbuf[kt&1][0][0] + w*8192;
      #pragma unroll
      for(int cch=0; cch<8; cch++) gload16(gs + cch*1024, ld + cch*1024);
    }
    if(kt < 31){                        // split A(kt+1) (in ar regs) -> Abuf
      SPLIT_STORE_A(ar0, ar1, ar2, ar3);
    }
    if(kt < 30){                        // load A(kt+2) -> ar regs (WAR after split)
      const float* a2 = ap + (kt+2)*32;
      ar0 = *(const float4*)(a2+0);  ar1 = *(const float4*)(a2+4);
      ar2 = *(const float4*)(a2+8);  ar3 = *(const float4*)(a2+12);
    }

    __builtin_amdgcn_s_setprio(1);
    #pragma unroll
    for(int m=0;m<4;m++)
      #pragma unroll
      for(int n=0;n<8;n++)
        acc[m][n] = __builtin_amdgcn_mfma_f32_16x16x32_bf16(fah[m], fbh[n], acc[m][n], 0,0,0);
    #pragma unroll
    for(int m=0;m<4;m++)
      #pragma unroll
      for(int n=0;n<8;n++)
        acc[m][n] = __builtin_amdgcn_mfma_f32_16x16x32_bf16(fah[m], fbl[n], acc[m][n], 0,0,0);
    #pragma unroll
    for(int m=0;m<4;m++)
      #pragma unroll
      for(int n=0;n<8;n++)
        acc[m][n] = __builtin_amdgcn_mfma_f32_16x16x32_bf16(fal[m], fbh[n], acc[m][n], 0,0,0);
    __builtin_amdgcn_s_setprio(0);

    if(kt < 31){
      // B(kt+1) must be landed; keep the 12 just-issued ops in flight
      if(kt < 30) asm volatile("s_waitcnt vmcnt(12) lgkmcnt(0)" ::: "memory");
      else        asm volatile("s_waitcnt vmcnt(0) lgkmcnt(0)"  ::: "memory");
      __builtin_amdgcn_sched_barrier(0);
      __builtin_amdgcn_s_barrier();
    }
  }

  // ---- epilogue: partial[2cb+wc][row] = sum over this wave's 128 cols ----
  const int bidx = rt >> 4;
  float av[8], ev[8];
  #pragma unroll
  for(int n=0;n<8;n++){
    const int col = cb*256 + wc*128 + n*16 + lm;
    av[n] = avec[bidx*DIM + col];
    ev[n] = energy[col];
  }
  #pragma unroll
  for(int m=0;m<4;m++){
    float rs[4];
    #pragma unroll
    for(int j=0;j<4;j++){
      float s = 0.f;
      #pragma unroll
      for(int n=0;n<8;n++) s += ev[n]*fast_tanh(av[n] + acc[m][n][j]);
      s += __shfl_xor(s,1); s += __shfl_xor(s,2);
      s += __shfl_xor(s,4); s += __shfl_xor(s,8);
      rs[j] = s;
    }
    if(lm == 0){                        // lanes 0,16,32,48: rows lk*4..lk*4+3
      float4 st = {rs[0], rs[1], rs[2], rs[3]};
      *(float4*)(partial + (size_t)(2*cb+wc)*NM + rt*128 + wr*64 + m*16 + lk*4) = st;
    }
  }
}

// ---------------- fused: reduce 8 partials + masked softmax ----------------
__global__ void k_softmax(const float* __restrict__ partial,
                          const int* __restrict__ mask,
                          float* __restrict__ attn){
  const int b = blockIdx.x, t = threadIdx.x;
  const int w = t >> 6, lane = t & 63;
  __shared__ float red[4];
  float sv[8]; int mv[8];
  float m = -3.4e38f;
  #pragma unroll
  for(int j=0;j<8;j++){
    const int i = j*256 + t;
    float s = 0.f;
    #pragma unroll
    for(int c=0;c<8;c++) s += partial[(size_t)c*NM + b*NS + i];
    sv[j] = s;
    mv[j] = mask[b*NS + i];
    if(mv[j] && s > m) m = s;
  }
  #pragma unroll
  for(int off=1; off<64; off<<=1) m = fmaxf(m, __shfl_xor(m, off));
  if(lane==0) red[w] = m;
  __syncthreads();
  m = fmaxf(fmaxf(red[0],red[1]), fmaxf(red[2],red[3]));
  __syncthreads();
  float ev[8]; float l = 0.f;
  #pragma unroll
  for(int j=0;j<8;j++){
    ev[j] = mv[j] ? __builtin_exp2f((sv[j]-m)*1.4426950408889634f) : 0.f;
    l += ev[j];
  }
  #pragma unroll
  for(int off=1; off<64; off<<=1) l += __shfl_xor(l, off);
  if(lane==0) red[w] = l;
  __syncthreads();
  l = red[0]+red[1]+red[2]+red[3];
  const float inv = 1.0f/l;
  #pragma unroll
  for(int j=0;j<8;j++) attn[b*NS + j*256 + t] = ev[j]*inv;
}

// ---------------- ctx = attn @ xs, chunked (256 blocks) ----------------
__global__ void k_ctx_partial(const float* __restrict__ attn,
                              const float* __restrict__ xs,
                              float* __restrict__ cp){
  const int b = blockIdx.x >> 3, ch = blockIdx.x & 7;
  const int t = threadIdx.x;
  __shared__ float al[256];
  al[t] = attn[b*NS + ch*256 + t];
  __syncthreads();
  float4 acc = {0.f,0.f,0.f,0.f};
  const float* base = xs + (size_t)(b*NS + ch*256)*DIM + t*4;
  for(int i=0;i<256;i++){
    float wv = al[i];                 // uniform across block -> no divergence
    if(wv > 1e-12f){                  // contribution bound < 1e-8, deterministic
      float4 x = *(const float4*)(base + (size_t)i*DIM);
      acc.x += wv*x.x; acc.y += wv*x.y; acc.z += wv*x.z; acc.w += wv*x.w;
    }
  }
  *(float4*)(cp + ((size_t)ch*NB + b)*DIM + t*4) = acc;
}

__global__ void k_ctx_reduce(const float* __restrict__ cp, float* __restrict__ ctx){
  int i = blockIdx.x*256 + threadIdx.x;
  float s = 0.f;
  #pragma unroll
  for(int ch=0; ch<8; ch++) s += cp[(size_t)ch*NB*DIM + i];
  ctx[i] = s;
}

extern "C" void kernel_launch(void* const* d_in, const int* in_sizes, int n_in,
                              void* d_out, int out_size, void* d_ws, size_t ws_size,
                              hipStream_t stream) {
  const float* kin    = (const float*)d_in[0];   // [32,1024]
  const float* xs     = (const float*)d_in[1];   // [32,2048,1024]
  const int*   mask   = (const int*)d_in[2];     // [32,2048]
  const float* wa     = (const float*)d_in[3];   // [1024,1024]
  const float* wb     = (const float*)d_in[4];   // [1024,1024]
  const float* energy = (const float*)d_in[5];   // [1024]
  float* out  = (float*)d_out;
  float* ctx  = out;            // [32,1024]
  float* attn = out + NB*DIM;   // [32,2048]

  char* ws = (char*)d_ws;
  float* partial = (float*)(ws);                        // 8*65536*4 = 2 MB
  float* avec    = (float*)(ws + 2097152);              // 128 KB
  float* cp      = (float*)(ws + 2097152 + 131072);     // 1 MB
  char*  wbimg   = ws + 2097152 + 131072 + 1048576;     // 4 MB pre-swizzled image

  k_split_wb   <<<1024, 256, 0, stream>>>(wb, wbimg);
  k_compute_a  <<<128, 256, 0, stream>>>(kin, wa, avec);
  k_gemm_scores<<<2048, 256, 0, stream>>>(xs, wbimg, avec, energy, partial);
  k_softmax    <<<NB, 256, 0, stream>>>(partial, mask, attn);
  k_ctx_partial<<<256, 256, 0, stream>>>(attn, xs, cp);
  k_ctx_reduce <<<128, 256, 0, stream>>>(cp, ctx);
}

// Round 5
// 469.199 us; speedup vs baseline: 1.0146x; 1.0146x over previous
//
#include <hip/hip_runtime.h>
#include <hip/hip_bf16.h>

#define NB 32
#define NS 2048
#define DIM 1024
#define NM (NB*NS)   // 65536 rows

typedef __attribute__((ext_vector_type(8))) short short8;
typedef __attribute__((ext_vector_type(4))) float f32x4;
typedef unsigned short us16;
typedef unsigned int   u32;

__device__ __forceinline__ float fast_tanh(float x){
  float e = __builtin_exp2f(x * 2.8853900817779268f); // e^{2x}
  return 1.0f - 2.0f/(e + 1.0f);
}

// split f32 into bf16 hi (truncated) + bf16 lo (residual); rep error ~2^-16 rel
__device__ __forceinline__ void split_bf16(float x, short &hi, short &lo){
  u32 u = __float_as_uint(x);
  float hf = __uint_as_float(u & 0xFFFF0000u);
  hi = (short)(u >> 16);
  lo = (short)(__float_as_uint(x - hf) >> 16);
}

// ---------------- Wb -> frag-ordered hi/lo image (B served from L2/L3) -------
// 16B slot index = ((kt*64 + ct16)*2 + hl)*64 + lane
// slot content: Wb[col = ct16*16 + (lane&15)][k = kt*32 + (lane>>4)*8 .. +8]
// as bf16 hi (hl=0) or lo (hl=1). A wave's frag load = 1KB contiguous.
__global__ void k_split_wb(const float* __restrict__ wb, char* __restrict__ img){
  const int tid = blockIdx.x*256 + threadIdx.x;   // 262144 slots
  const int kt   = tid >> 13;
  const int ct16 = (tid >> 7) & 63;
  const int hl   = (tid >> 6) & 1;
  const int lane = tid & 63;
  const int col  = ct16*16 + (lane & 15);
  const int k0   = kt*32 + (lane >> 4)*8;
  const float* src = wb + (size_t)col*DIM + k0;
  float4 v0 = *(const float4*)src;
  float4 v1 = *(const float4*)(src + 4);
  float fv[8] = {v0.x,v0.y,v0.z,v0.w,v1.x,v1.y,v1.z,v1.w};
  short8 out;
  #pragma unroll
  for(int j=0;j<8;j++){
    short hi,lo; split_bf16(fv[j],hi,lo);
    out[j] = hl ? lo : hi;
  }
  *(short8*)(img + (size_t)tid*16) = out;
}

// ---------------- a = k @ Wa^T ----------------
__global__ void k_compute_a(const float* __restrict__ kin,
                            const float* __restrict__ wa,
                            float* __restrict__ avec){
  __shared__ float4 kl[256];
  const int b = blockIdx.x >> 2, oc = blockIdx.x & 3;
  const int t = threadIdx.x;
  kl[t] = *(const float4*)(kin + b*DIM + t*4);
  __syncthreads();
  const int o = oc*256 + t;
  const float4* wrow = (const float4*)(wa + (size_t)o*DIM);
  float acc = 0.f;
  for(int i=0;i<256;i++){
    float4 wv = wrow[i]; float4 kk = kl[i];
    acc += wv.x*kk.x + wv.y*kk.y + wv.z*kk.z + wv.w*kk.w;
  }
  avec[b*DIM + o] = acc;
}

// split 16 f32 -> hi/lo bf16, store XOR-swizzled into Abuf[BUF] at row sr
#define SPLIT_STORE_A(BUF, AR0,AR1,AR2,AR3)                                     \
  {                                                                             \
    float fv[16];                                                               \
    *(float4*)(fv+0)=AR0; *(float4*)(fv+4)=AR1;                                 \
    *(float4*)(fv+8)=AR2; *(float4*)(fv+12)=AR3;                                \
    short8 h0,h1,l0,l1;                                                         \
    _Pragma("unroll")                                                           \
    for(int j=0;j<8;j++){ short a,b; split_bf16(fv[j],a,b);   h0[j]=a; l0[j]=b; }\
    _Pragma("unroll")                                                           \
    for(int j=0;j<8;j++){ short a,b; split_bf16(fv[8+j],a,b); h1[j]=a; l1[j]=b; }\
    const int swz = (sr & 7) << 4;                                              \
    char* abase = (char*)&Abuf[BUF][0][0] + sr*128;                             \
    *(short8*)(abase + ((sh*32      ) ^ swz)) = h0;                             \
    *(short8*)(abase + ((sh*32 + 16 ) ^ swz)) = h1;                             \
    *(short8*)(abase + ((64 + sh*32     ) ^ swz)) = l0;                         \
    *(short8*)(abase + ((64 + sh*32 + 16) ^ swz)) = l1;                         \
  }

// one kt step: CUR = A-buffer parity; FBC = B frags for kt (in regs);
// FBN = B frags being loaded for kt+1; ARS = raw A(kt+1) (to split);
// ARN = raw A(kt+2) destination regs.
#define GEMM_BODY(KT, CUR, FBC, FBN, ARS0,ARS1,ARS2,ARS3, ARN0,ARN1,ARN2,ARN3)  \
  {                                                                             \
    if((KT) < 31) SPLIT_STORE_A(1-(CUR), ARS0,ARS1,ARS2,ARS3);                  \
    if((KT) < 30){                                                              \
      const float* a2 = ap + ((KT)+2)*32;                                       \
      ARN0 = *(const float4*)(a2+0);  ARN1 = *(const float4*)(a2+4);            \
      ARN2 = *(const float4*)(a2+8);  ARN3 = *(const float4*)(a2+12);           \
    }                                                                           \
    if((KT) < 31){                                                              \
      const char* bq = bp + ((KT)+1)*131072;                                    \
      _Pragma("unroll")                                                         \
      for(int n=0;n<4;n++){                                                     \
        FBN[2*n]   = *(const short8*)(bq + n*2048);                             \
        FBN[2*n+1] = *(const short8*)(bq + n*2048 + 1024);                      \
      }                                                                         \
    }                                                                           \
    short8 fah[4], fal[4];                                                      \
    const char* ab = (const char*)&Abuf[CUR][0][0] + abro;                      \
    _Pragma("unroll")                                                           \
    for(int m=0;m<4;m++){                                                       \
      fah[m] = *(const short8*)(ab + m*2048 + off_h);                           \
      fal[m] = *(const short8*)(ab + m*2048 + off_l);                           \
    }                                                                           \
    _Pragma("unroll")                                                           \
    for(int m=0;m<4;m++)                                                        \
      _Pragma("unroll")                                                         \
      for(int n=0;n<4;n++)                                                      \
        acc[m][n] = __builtin_amdgcn_mfma_f32_16x16x32_bf16(fah[m], FBC[2*n],   acc[m][n], 0,0,0); \
    _Pragma("unroll")                                                           \
    for(int m=0;m<4;m++)                                                        \
      _Pragma("unroll")                                                         \
      for(int n=0;n<4;n++)                                                      \
        acc[m][n] = __builtin_amdgcn_mfma_f32_16x16x32_bf16(fah[m], FBC[2*n+1], acc[m][n], 0,0,0); \
    _Pragma("unroll")                                                           \
    for(int m=0;m<4;m++)                                                        \
      _Pragma("unroll")                                                         \
      for(int n=0;n<4;n++)                                                      \
        acc[m][n] = __builtin_amdgcn_mfma_f32_16x16x32_bf16(fal[m], FBC[2*n+1-1], acc[m][n], 0,0,0); \
    asm volatile("s_waitcnt lgkmcnt(0)" ::: "memory");                          \
    __builtin_amdgcn_sched_barrier(0);                                          \
    __builtin_amdgcn_s_barrier();                                               \
  }

// ---------------- main GEMM (128x128, B direct from L2) + fused epilogue ------
__global__ __launch_bounds__(256,2)
void k_gemm_scores(const float* __restrict__ xs,
                   const char* __restrict__ wbimg,
                   const float* __restrict__ avec,
                   const float* __restrict__ energy,
                   float* __restrict__ partial){
  __shared__ us16 Abuf[2][128][64];   // hi cols 0..31 | lo 32..63, XOR-swizzled

  const int h  = blockIdx.x;                  // 4096 blocks
  const int rt = (h & 7) + 8*(h >> 6);        // same-rt blocks on same XCD
  const int cb = (h >> 3) & 7;                // 128-col tile index
  const int t  = threadIdx.x;
  const int w  = t >> 6, lane = t & 63;
  const int wr = w >> 1, wc = w & 1;          // wave tile: 64x64
  const int lm = lane & 15, lk = lane >> 4;
  const int sr = t >> 1, sh = t & 1;

  const float* ap = xs + (size_t)(rt*128 + sr)*DIM + sh*16;
  // B frag base for this wave: ct16 base = cb*8 + wc*4
  const char* bp = wbimg + (size_t)(cb*8 + wc*4)*2048 + lane*16;

  const int abro  = (wr*64 + lm)*128;
  const int off_h = (lk*16) ^ ((lm&7)<<4);
  const int off_l = (64 + lk*16) ^ ((lm&7)<<4);

  f32x4 acc[4][4];
  #pragma unroll
  for(int m=0;m<4;m++)
    #pragma unroll
    for(int n=0;n<4;n++) acc[m][n] = (f32x4){0.f,0.f,0.f,0.f};

  // ---- prologue: A(0)->Abuf[0], ar<-A(1), B(0)->b0 ----
  float4 x0 = *(const float4*)(ap+0),  x1 = *(const float4*)(ap+4);
  float4 x2 = *(const float4*)(ap+8),  x3 = *(const float4*)(ap+12);
  SPLIT_STORE_A(0, x0, x1, x2, x3);
  float4 y0, y1, y2, y3;
  {
    const float* a2 = ap + 32;
    y0 = *(const float4*)(a2+0);  y1 = *(const float4*)(a2+4);
    y2 = *(const float4*)(a2+8);  y3 = *(const float4*)(a2+12);
  }
  short8 b0[8], b1[8];
  #pragma unroll
  for(int n=0;n<4;n++){
    b0[2*n]   = *(const short8*)(bp + n*2048);
    b0[2*n+1] = *(const short8*)(bp + n*2048 + 1024);
  }
  asm volatile("s_waitcnt lgkmcnt(0)" ::: "memory");
  __builtin_amdgcn_sched_barrier(0);
  __builtin_amdgcn_s_barrier();

  // ---- main loop: 2 kt per iteration (static buffer parity) ----
  for(int kt=0; kt<32; kt+=2){
    GEMM_BODY(kt,   0, b0, b1, y0,y1,y2,y3, x0,x1,x2,x3);
    GEMM_BODY(kt+1, 1, b1, b0, x0,x1,x2,x3, y0,y1,y2,y3);
  }

  // ---- epilogue: partial[cb*2+wc][row] = sum over this wave's 64 cols ----
  const int bidx = rt >> 4;
  float av[4], ev[4];
  #pragma unroll
  for(int n=0;n<4;n++){
    const int col = cb*128 + wc*64 + n*16 + lm;
    av[n] = avec[bidx*DIM + col];
    ev[n] = energy[col];
  }
  #pragma unroll
  for(int m=0;m<4;m++){
    float rs[4];
    #pragma unroll
    for(int j=0;j<4;j++){
      float s = 0.f;
      #pragma unroll
      for(int n=0;n<4;n++) s += ev[n]*fast_tanh(av[n] + acc[m][n][j]);
      s += __shfl_xor(s,1); s += __shfl_xor(s,2);
      s += __shfl_xor(s,4); s += __shfl_xor(s,8);
      rs[j] = s;
    }
    if(lm == 0){                        // lanes 0,16,32,48: rows lk*4..lk*4+3
      float4 st = {rs[0], rs[1], rs[2], rs[3]};
      *(float4*)(partial + (size_t)(cb*2+wc)*NM + rt*128 + wr*64 + m*16 + lk*4) = st;
    }
  }
}

// ---------------- fused: reduce 16 partials + masked softmax ----------------
__global__ void k_softmax(const float* __restrict__ partial,
                          const int* __restrict__ mask,
                          float* __restrict__ attn){
  const int b = blockIdx.x, t = threadIdx.x;
  const int w = t >> 6, lane = t & 63;
  __shared__ float red[4];
  float sv[8]; int mv[8];
  float m = -3.4e38f;
  #pragma unroll
  for(int j=0;j<8;j++){
    const int i = j*256 + t;
    float s = 0.f;
    #pragma unroll
    for(int c=0;c<16;c++) s += partial[(size_t)c*NM + b*NS + i];
    sv[j] = s;
    mv[j] = mask[b*NS + i];
    if(mv[j] && s > m) m = s;
  }
  #pragma unroll
  for(int off=1; off<64; off<<=1) m = fmaxf(m, __shfl_xor(m, off));
  if(lane==0) red[w] = m;
  __syncthreads();
  m = fmaxf(fmaxf(red[0],red[1]), fmaxf(red[2],red[3]));
  __syncthreads();
  float ev[8]; float l = 0.f;
  #pragma unroll
  for(int j=0;j<8;j++){
    ev[j] = mv[j] ? __builtin_exp2f((sv[j]-m)*1.4426950408889634f) : 0.f;
    l += ev[j];
  }
  #pragma unroll
  for(int off=1; off<64; off<<=1) l += __shfl_xor(l, off);
  if(lane==0) red[w] = l;
  __syncthreads();
  l = red[0]+red[1]+red[2]+red[3];
  const float inv = 1.0f/l;
  #pragma unroll
  for(int j=0;j<8;j++) attn[b*NS + j*256 + t] = ev[j]*inv;
}

// ---------------- ctx = attn @ xs, chunked (256 blocks) ----------------
__global__ void k_ctx_partial(const float* __restrict__ attn,
                              const float* __restrict__ xs,
                              float* __restrict__ cp){
  const int b = blockIdx.x >> 3, ch = blockIdx.x & 7;
  const int t = threadIdx.x;
  __shared__ float al[256];
  al[t] = attn[b*NS + ch*256 + t];
  __syncthreads();
  float4 acc = {0.f,0.f,0.f,0.f};
  const float* base = xs + (size_t)(b*NS + ch*256)*DIM + t*4;
  for(int i=0;i<256;i++){
    float wv = al[i];                 // uniform across block -> no divergence
    if(wv > 1e-12f){                  // contribution bound < 1e-8, deterministic
      float4 x = *(const float4*)(base + (size_t)i*DIM);
      acc.x += wv*x.x; acc.y += wv*x.y; acc.z += wv*x.z; acc.w += wv*x.w;
    }
  }
  *(float4*)(cp + ((size_t)ch*NB + b)*DIM + t*4) = acc;
}

__global__ void k_ctx_reduce(const float* __restrict__ cp, float* __restrict__ ctx){
  int i = blockIdx.x*256 + threadIdx.x;
  float s = 0.f;
  #pragma unroll
  for(int ch=0; ch<8; ch++) s += cp[(size_t)ch*NB*DIM + i];
  ctx[i] = s;
}

extern "C" void kernel_launch(void* const* d_in, const int* in_sizes, int n_in,
                              void* d_out, int out_size, void* d_ws, size_t ws_size,
                              hipStream_t stream) {
  const float* kin    = (const float*)d_in[0];   // [32,1024]
  const float* xs     = (const float*)d_in[1];   // [32,2048,1024]
  const int*   mask   = (const int*)d_in[2];     // [32,2048]
  const float* wa     = (const float*)d_in[3];   // [1024,1024]
  const float* wb     = (const float*)d_in[4];   // [1024,1024]
  const float* energy = (const float*)d_in[5];   // [1024]
  float* out  = (float*)d_out;
  float* ctx  = out;            // [32,1024]
  float* attn = out + NB*DIM;   // [32,2048]

  char* ws = (char*)d_ws;
  float* partial = (float*)(ws);                        // 16*65536*4 = 4 MB
  float* avec    = (float*)(ws + 4194304);              // 128 KB
  float* cp      = (float*)(ws + 4194304 + 131072);     // 1 MB
  char*  wbimg   = ws + 4194304 + 131072 + 1048576;     // 4 MB frag image

  k_split_wb   <<<1024, 256, 0, stream>>>(wb, wbimg);
  k_compute_a  <<<128, 256, 0, stream>>>(kin, wa, avec);
  k_gemm_scores<<<4096, 256, 0, stream>>>(xs, wbimg, avec, energy, partial);
  k_softmax    <<<NB, 256, 0, stream>>>(partial, mask, attn);
  k_ctx_partial<<<256, 256, 0, stream>>>(attn, xs, cp);
  k_ctx_reduce <<<128, 256, 0, stream>>>(cp, ctx);
}

// Round 7
// 366.959 us; speedup vs baseline: 1.2972x; 1.2786x over previous
//
#include <hip/hip_runtime.h>
#include <hip/hip_bf16.h>

#define NB 32
#define NS 2048
#define DIM 1024
#define NM (NB*NS)   // 65536 rows
#define CAP 256      // max rescored rows per batch
#define SEL_MARGIN 24.0f

typedef __attribute__((ext_vector_type(8))) short short8;
typedef __attribute__((ext_vector_type(4))) float f32x4;
typedef __attribute__((ext_vector_type(4))) unsigned short us16x4;
typedef unsigned short us16;
typedef unsigned int   u32;
typedef __attribute__((address_space(3))) void lds_void;
typedef __attribute__((address_space(1))) void glb_void;

__device__ __forceinline__ void gload16(const void* g, void* l){
  __builtin_amdgcn_global_load_lds((const glb_void*)g, (lds_void*)l, 16, 0, 0);
}

__device__ __forceinline__ float fast_tanh(float x){
  float e = __builtin_exp2f(x * 2.8853900817779268f); // e^{2x}
  return 1.0f - 2.0f/(e + 1.0f);
}

__device__ __forceinline__ void split_bf16(float x, short &hi, short &lo){
  u32 u = __float_as_uint(x);
  float hf = __uint_as_float(u & 0xFFFF0000u);
  hi = (short)(u >> 16);
  lo = (short)(__float_as_uint(x - hf) >> 16);
}

// ---------------- Wb -> frag-ordered hi/lo image (phase-2 B, L2/L3-served) ----
// 16B slot = ((kt*64 + ct16)*2 + hl)*64 + lane ; content Wb[ct16*16+(lane&15)]
// [kt*32+(lane>>4)*8 ..+8] as bf16 hi/lo.  (verified in R5)
__global__ void k_split_wb_frag(const float* __restrict__ wb, char* __restrict__ img){
  const int tid = blockIdx.x*256 + threadIdx.x;   // 262144 slots
  const int kt   = tid >> 13;
  const int ct16 = (tid >> 7) & 63;
  const int hl   = (tid >> 6) & 1;
  const int lane = tid & 63;
  const int col  = ct16*16 + (lane & 15);
  const int k0   = kt*32 + (lane >> 4)*8;
  const float* src = wb + (size_t)col*DIM + k0;
  float4 v0 = *(const float4*)src;
  float4 v1 = *(const float4*)(src + 4);
  float fv[8] = {v0.x,v0.y,v0.z,v0.w,v1.x,v1.y,v1.z,v1.w};
  short8 out;
  #pragma unroll
  for(int j=0;j<8;j++){
    short hi,lo; split_bf16(fv[j],hi,lo);
    out[j] = hl ? lo : hi;
  }
  *(short8*)(img + (size_t)tid*16) = out;
}

// ---------------- Wb -> hi-only pre-swizzled gload image (phase-1 B) ----------
// image = [kt(32)][cb(4)][16KB tile]; tile byte B: row=B>>7, inner=B&127,
// ix = inner ^ ((row&7)<<4): colhi=ix>>6, lk=(ix>>4)&3 ->
// element: col = cb*256 + colhi*128 + row, k = kt*32 + lk*8 + (B&15)/2 (hi bf16)
__global__ void k_split_wb_gload(const float* __restrict__ wb, char* __restrict__ img){
  const int tid = blockIdx.x*256 + threadIdx.x;   // 131072 chunks of 16B
  const int tile = tid >> 10;
  const int kt = tile >> 2, cb = tile & 3;
  const int byt = (tid & 1023) * 16;
  const int row = byt >> 7, inner = byt & 127;
  const int ix = inner ^ ((row & 7) << 4);
  const int colhi = ix >> 6, lkk = (ix >> 4) & 3;
  const int col = cb*256 + colhi*128 + row;
  const float* src = wb + (size_t)col*DIM + kt*32 + lkk*8;
  float4 v0 = *(const float4*)src;
  float4 v1 = *(const float4*)(src + 4);
  float fv[8] = {v0.x,v0.y,v0.z,v0.w,v1.x,v1.y,v1.z,v1.w};
  short8 out;
  #pragma unroll
  for(int j=0;j<8;j++) out[j] = (short)(__float_as_uint(fv[j]) >> 16);
  *(short8*)(img + (size_t)tid*16) = out;
}

// ---------------- a = k @ Wa^T (exact f32) ----------------
__global__ void k_compute_a(const float* __restrict__ kin,
                            const float* __restrict__ wa,
                            float* __restrict__ avec){
  __shared__ float4 kl[256];
  const int b = blockIdx.x >> 2, oc = blockIdx.x & 3;
  const int t = threadIdx.x;
  kl[t] = *(const float4*)(kin + b*DIM + t*4);
  __syncthreads();
  const int o = oc*256 + t;
  const float4* wrow = (const float4*)(wa + (size_t)o*DIM);
  float acc = 0.f;
  for(int i=0;i<256;i++){
    float4 wv = wrow[i]; float4 kk = kl[i];
    acc += wv.x*kk.x + wv.y*kk.y + wv.z*kk.z + wv.w*kk.w;
  }
  avec[b*DIM + o] = acc;
}

// ---------------- phase-1: 1-pass truncated-bf16 GEMM + tanh/energy epilogue --
// 128x256 block, 4 waves (64x128), R3 skeleton. A hi-only [128][40] LDS,
// B hi-only via global_load_lds double-buffer.
__global__ __launch_bounds__(256,2)
void k_gemm_approx(const float* __restrict__ xs,
                   const char* __restrict__ img1,
                   const float* __restrict__ avec,
                   const float* __restrict__ energy,
                   float* __restrict__ partial){
  __shared__ us16 Abuf[128][40];      // hi only; row stride 80B
  __shared__ us16 Bbuf[2][128][64];   // [row=col&127][colhi*32+k] swizzled; 16KB each

  const int h  = blockIdx.x;                  // 2048 blocks
  const int rt = (h & 7) + 8*(h >> 5);        // same-rt blocks on same XCD
  const int cb = (h >> 3) & 3;                // 256-col tile index
  const int t  = threadIdx.x;
  const int w  = t >> 6, lane = t & 63;
  const int wr = w >> 1, wc = w & 1;          // wave tile: 64 rows x 128 cols
  const int lm = lane & 15, lk = lane >> 4;
  const int sr = t >> 1, sh = t & 1;

  const float* ap = xs + (size_t)(rt*128 + sr)*DIM + sh*16;
  const char*  bsrc = img1;                   // + (kt*4+cb)*16384

  const char* a_rd = (const char*)&Abuf[0][0] + (wr*64 + lm)*80 + ((lk*16) ^ ((lm&3)<<4));
  const int boff = (wc*64 + lk*16) ^ ((lm&7)<<4);

  f32x4 acc[4][8];
  #pragma unroll
  for(int m=0;m<4;m++)
    #pragma unroll
    for(int n=0;n<8;n++) acc[m][n] = (f32x4){0.f,0.f,0.f,0.f};

  // prologue: issue B(0)->buf0; load A(0) regs
  {
    const char* gs = bsrc + (size_t)cb*16384 + t*16;
    char* ld = (char*)&Bbuf[0][0][0] + t*16;
    #pragma unroll
    for(int c=0;c<4;c++) gload16(gs + c*4096, ld + c*4096);
  }
  float4 ar0 = *(const float4*)(ap+0),  ar1 = *(const float4*)(ap+4);
  float4 ar2 = *(const float4*)(ap+8),  ar3 = *(const float4*)(ap+12);

  for(int kt=0; kt<32; kt++){
    const int cur = kt & 1;
    __syncthreads();                  // bar1: prior frag reads consumed
    {                                 // truncate-store A(kt)
      float fv[16];
      *(float4*)(fv+0)=ar0; *(float4*)(fv+4)=ar1;
      *(float4*)(fv+8)=ar2; *(float4*)(fv+12)=ar3;
      short8 h0, h1;
      #pragma unroll
      for(int j=0;j<8;j++){ h0[j] = (short)(__float_as_uint(fv[j])>>16);
                            h1[j] = (short)(__float_as_uint(fv[8+j])>>16); }
      char* abase = (char*)&Abuf[0][0] + sr*80;
      const int swz = (sr & 3) << 4;
      *(short8*)(abase + ((sh*32     ) ^ swz)) = h0;
      *(short8*)(abase + ((sh*32 + 16) ^ swz)) = h1;
    }
    if(kt < 31){
      {                               // issue B(kt+1) -> other buffer
        const char* gs = bsrc + (size_t)((kt+1)*4 + cb)*16384 + t*16;
        char* ld = (char*)&Bbuf[cur^1][0][0] + t*16;
        #pragma unroll
        for(int c=0;c<4;c++) gload16(gs + c*4096, ld + c*4096);
      }
      const float* a2 = ap + (kt+1)*32;   // prefetch A(kt+1) regs
      ar0 = *(const float4*)(a2+0);  ar1 = *(const float4*)(a2+4);
      ar2 = *(const float4*)(a2+8);  ar3 = *(const float4*)(a2+12);
      asm volatile("s_waitcnt vmcnt(8)" ::: "memory");
    } else {
      asm volatile("s_waitcnt vmcnt(0)" ::: "memory");
    }
    __builtin_amdgcn_sched_barrier(0);
    __syncthreads();                  // bar2: tile kt ready

    short8 fa[4], fb[8];
    const char* bb = (const char*)&Bbuf[cur][0][0] + lm*128 + boff;
    #pragma unroll
    for(int m=0;m<4;m++) fa[m] = *(const short8*)(a_rd + m*1280);
    #pragma unroll
    for(int n=0;n<8;n++) fb[n] = *(const short8*)(bb + n*2048);
    #pragma unroll
    for(int m=0;m<4;m++)
      #pragma unroll
      for(int n=0;n<8;n++)
        acc[m][n] = __builtin_amdgcn_mfma_f32_16x16x32_bf16(fa[m], fb[n], acc[m][n], 0,0,0);
  }

  // epilogue: partial[cb*2+wc][row] = sum_o energy*tanh(a+b) over wave's 128 cols
  const int bidx = rt >> 4;
  float av[8], ev[8];
  #pragma unroll
  for(int n=0;n<8;n++){
    const int col = cb*256 + wc*128 + n*16 + lm;
    av[n] = avec[bidx*DIM + col];
    ev[n] = energy[col];
  }
  #pragma unroll
  for(int m=0;m<4;m++){
    float rs[4];
    #pragma unroll
    for(int j=0;j<4;j++){
      float s = 0.f;
      #pragma unroll
      for(int n=0;n<8;n++) s += ev[n]*fast_tanh(av[n] + acc[m][n][j]);
      s += __shfl_xor(s,1); s += __shfl_xor(s,2);
      s += __shfl_xor(s,4); s += __shfl_xor(s,8);
      rs[j] = s;
    }
    if(lm == 0){
      float4 st = {rs[0], rs[1], rs[2], rs[3]};
      *(float4*)(partial + (size_t)(cb*2+wc)*NM + rt*128 + wr*64 + m*16 + lk*4) = st;
    }
  }
}

// ---------------- select: reduce partials, masked max, pick candidates --------
__global__ void k_select(const float* __restrict__ partial,
                         const int* __restrict__ mask,
                         float* __restrict__ scores,
                         int* __restrict__ sel_count,
                         int* __restrict__ sel_list){
  const int b = blockIdx.x, t = threadIdx.x;
  const int w = t >> 6, lane = t & 63;
  __shared__ float red[4];
  float sv[8]; int mv[8];
  float m = -3.4e38f;
  #pragma unroll
  for(int j=0;j<8;j++){
    const int i = j*256 + t;
    float s = 0.f;
    #pragma unroll
    for(int c=0;c<8;c++) s += partial[(size_t)c*NM + b*NS + i];
    sv[j] = s;
    scores[b*NS + i] = s;
    mv[j] = mask[b*NS + i];
    if(mv[j] && s > m) m = s;
  }
  #pragma unroll
  for(int off=1; off<64; off<<=1) m = fmaxf(m, __shfl_xor(m, off));
  if(lane==0) red[w] = m;
  __syncthreads();
  m = fmaxf(fmaxf(red[0],red[1]), fmaxf(red[2],red[3]));
  const float thr = m - SEL_MARGIN;
  #pragma unroll
  for(int j=0;j<8;j++){
    if(mv[j] && sv[j] > thr){
      int slot = atomicAdd(&sel_count[b], 1);
      if(slot < CAP) sel_list[b*CAP + slot] = j*256 + t;
    }
  }
}

// ---------------- phase-2: exact 3-pass rescoring of selected rows ------------
// grid 512 = b(32) x cb(16 col-tiles of 64); 4 waves, wave = 16 cols (1 ct16).
__global__ __launch_bounds__(256)
void k_phase2(const float* __restrict__ xs,
              const char* __restrict__ imgf,
              const float* __restrict__ avec,
              const float* __restrict__ energy,
              const int* __restrict__ sel_count,
              const int* __restrict__ sel_list,
              float* __restrict__ p2buf){
  __shared__ us16 A2[32][80];     // hi bytes [0,64), lo at +80, row stride 160B
  __shared__ float s2[4][32];
  const int b = blockIdx.x >> 4, cb = blockIdx.x & 15;
  const int t = threadIdx.x, w = t >> 6, lane = t & 63;
  const int lm = lane & 15, lk = lane >> 4;
  const int ct = cb*4 + w;                    // ct16 index 0..63
  const int col = ct*16 + lm;
  const float av  = avec[b*DIM + col];
  const float evv = energy[col];
  char* lds = (char*)&A2[0][0];
  const int count = min(sel_count[b], CAP);
  const int ri = t >> 3, seg = t & 7;
  // XOR key must stay within the 64-byte hi field -> 2-bit key (&3).  (R6 bug:
  // &7 put key bit6 past the field and lo writes past the 160B row.)
  const int wbyte = ri*160 + ((seg*8) ^ ((ri&3)<<4));
  const char* a_rd = lds + lm*160 + ((lk*16) ^ ((lm&3)<<4));

  for(int c0 = 0; c0 < count; c0 += 32){
    const int li = c0 + ri;
    const int row = sel_list[b*CAP + min(li, count-1)];
    const float* rp = xs + ((size_t)b*NS + row)*DIM + seg*4;
    f32x4 acc[2];
    acc[0] = (f32x4){0.f,0.f,0.f,0.f};
    acc[1] = (f32x4){0.f,0.f,0.f,0.f};
    for(int kt=0; kt<32; kt++){
      __syncthreads();                        // prior kt's frag reads consumed
      float4 v = *(const float4*)(rp + kt*32);
      float fv[4] = {v.x, v.y, v.z, v.w};
      us16x4 hi, lo;
      #pragma unroll
      for(int e=0;e<4;e++){
        short a, l; split_bf16(fv[e], a, l);
        hi[e] = (us16)a; lo[e] = (us16)l;
      }
      *(us16x4*)(lds + wbyte)      = hi;
      *(us16x4*)(lds + wbyte + 80) = lo;
      __syncthreads();
      const char* fbb = imgf + ((size_t)(kt*64 + ct)*2)*1024 + lane*16;
      short8 bh = *(const short8*)(fbb);
      short8 bl = *(const short8*)(fbb + 1024);
      short8 fah[2], fal[2];
      #pragma unroll
      for(int m=0;m<2;m++){
        fah[m] = *(const short8*)(a_rd + m*2560);
        fal[m] = *(const short8*)(a_rd + m*2560 + 80);
      }
      #pragma unroll
      for(int m=0;m<2;m++)
        acc[m] = __builtin_amdgcn_mfma_f32_16x16x32_bf16(fah[m], bh, acc[m], 0,0,0);
      #pragma unroll
      for(int m=0;m<2;m++)
        acc[m] = __builtin_amdgcn_mfma_f32_16x16x32_bf16(fah[m], bl, acc[m], 0,0,0);
      #pragma unroll
      for(int m=0;m<2;m++)
        acc[m] = __builtin_amdgcn_mfma_f32_16x16x32_bf16(fal[m], bh, acc[m], 0,0,0);
    }
    // epilogue: per row (m*16+lk*4+j) partial over this wave's 16 cols
    float s[2][4];
    #pragma unroll
    for(int m=0;m<2;m++)
      #pragma unroll
      for(int j=0;j<4;j++){
        float v = evv * fast_tanh(av + acc[m][j]);
        v += __shfl_xor(v,1); v += __shfl_xor(v,2);
        v += __shfl_xor(v,4); v += __shfl_xor(v,8);
        s[m][j] = v;
      }
    __syncthreads();
    if(lm == 0){
      #pragma unroll
      for(int m=0;m<2;m++)
        #pragma unroll
        for(int j=0;j<4;j++) s2[w][m*16 + lk*4 + j] = s[m][j];
    }
    __syncthreads();
    if(t < 32){
      float sum = s2[0][t] + s2[1][t] + s2[2][t] + s2[3][t];
      p2buf[((size_t)b*16 + cb)*CAP + c0 + t] = sum;
    }
  }
}

// ---------------- scatter exact scores back ----------------
__global__ void k_scatter(const float* __restrict__ p2buf,
                          const int* __restrict__ sel_count,
                          const int* __restrict__ sel_list,
                          float* __restrict__ scores){
  const int b = blockIdx.x, t = threadIdx.x;
  const int count = min(sel_count[b], CAP);
  if(t < count){
    float s = 0.f;
    #pragma unroll
    for(int c=0;c<16;c++) s += p2buf[((size_t)b*16 + c)*CAP + t];
    scores[b*NS + sel_list[b*CAP + t]] = s;
  }
}

// ---------------- masked softmax over corrected scores ----------------
__global__ void k_softmax(const float* __restrict__ scores,
                          const int* __restrict__ mask,
                          float* __restrict__ attn){
  const int b = blockIdx.x, t = threadIdx.x;
  const int w = t >> 6, lane = t & 63;
  __shared__ float red[4];
  float sv[8]; int mv[8];
  float m = -3.4e38f;
  #pragma unroll
  for(int j=0;j<8;j++){
    const int i = j*256 + t;
    sv[j] = scores[b*NS + i];
    mv[j] = mask[b*NS + i];
    if(mv[j] && sv[j] > m) m = sv[j];
  }
  #pragma unroll
  for(int off=1; off<64; off<<=1) m = fmaxf(m, __shfl_xor(m, off));
  if(lane==0) red[w] = m;
  __syncthreads();
  m = fmaxf(fmaxf(red[0],red[1]), fmaxf(red[2],red[3]));
  __syncthreads();
  float ev[8]; float l = 0.f;
  #pragma unroll
  for(int j=0;j<8;j++){
    ev[j] = mv[j] ? __builtin_exp2f((sv[j]-m)*1.4426950408889634f) : 0.f;
    l += ev[j];
  }
  #pragma unroll
  for(int off=1; off<64; off<<=1) l += __shfl_xor(l, off);
  if(lane==0) red[w] = l;
  __syncthreads();
  l = red[0]+red[1]+red[2]+red[3];
  const float inv = 1.0f/l;
  #pragma unroll
  for(int j=0;j<8;j++) attn[b*NS + j*256 + t] = ev[j]*inv;
}

// ---------------- ctx = attn @ xs, chunked (256 blocks) ----------------
__global__ void k_ctx_partial(const float* __restrict__ attn,
                              const float* __restrict__ xs,
                              float* __restrict__ cp){
  const int b = blockIdx.x >> 3, ch = blockIdx.x & 7;
  const int t = threadIdx.x;
  __shared__ float al[256];
  al[t] = attn[b*NS + ch*256 + t];
  __syncthreads();
  float4 acc = {0.f,0.f,0.f,0.f};
  const float* base = xs + (size_t)(b*NS + ch*256)*DIM + t*4;
  for(int i=0;i<256;i++){
    float wv = al[i];                 // uniform across block
    if(wv > 1e-12f){                  // contribution < 1e-8, deterministic
      float4 x = *(const float4*)(base + (size_t)i*DIM);
      acc.x += wv*x.x; acc.y += wv*x.y; acc.z += wv*x.z; acc.w += wv*x.w;
    }
  }
  *(float4*)(cp + ((size_t)ch*NB + b)*DIM + t*4) = acc;
}

__global__ void k_ctx_reduce(const float* __restrict__ cp, float* __restrict__ ctx){
  int i = blockIdx.x*256 + threadIdx.x;
  float s = 0.f;
  #pragma unroll
  for(int ch=0; ch<8; ch++) s += cp[(size_t)ch*NB*DIM + i];
  ctx[i] = s;
}

extern "C" void kernel_launch(void* const* d_in, const int* in_sizes, int n_in,
                              void* d_out, int out_size, void* d_ws, size_t ws_size,
                              hipStream_t stream) {
  const float* kin    = (const float*)d_in[0];   // [32,1024]
  const float* xs     = (const float*)d_in[1];   // [32,2048,1024]
  const int*   mask   = (const int*)d_in[2];     // [32,2048]
  const float* wa     = (const float*)d_in[3];   // [1024,1024]
  const float* wb     = (const float*)d_in[4];   // [1024,1024]
  const float* energy = (const float*)d_in[5];   // [1024]
  float* out  = (float*)d_out;
  float* ctx  = out;            // [32,1024]
  float* attn = out + NB*DIM;   // [32,2048]

  char* ws = (char*)d_ws;
  float* partial   = (float*)(ws);                       // 2 MB    @ 0
  float* avec      = (float*)(ws + 2097152);             // 128 KB
  float* scores    = (float*)(ws + 2228224);             // 256 KB
  float* cp        = (float*)(ws + 2490368);             // 1 MB
  char*  imgf      = ws + 3538944;                       // 4 MB (frag hi/lo)
  char*  img1      = ws + 7733248;                       // 2 MB (gload hi)
  int*   sel_count = (int*)(ws + 9830400);               // 128 B
  int*   sel_list  = (int*)(ws + 9830528);               // 32 KB
  float* p2buf     = (float*)(ws + 9863296);             // 512 KB

  hipMemsetAsync(sel_count, 0, NB*sizeof(int), stream);
  k_split_wb_frag <<<1024, 256, 0, stream>>>(wb, imgf);
  k_split_wb_gload<<<512, 256, 0, stream>>>(wb, img1);
  k_compute_a     <<<128, 256, 0, stream>>>(kin, wa, avec);
  k_gemm_approx   <<<2048, 256, 0, stream>>>(xs, img1, avec, energy, partial);
  k_select        <<<NB, 256, 0, stream>>>(partial, mask, scores, sel_count, sel_list);
  k_phase2        <<<512, 256, 0, stream>>>(xs, imgf, avec, energy, sel_count, sel_list, p2buf);
  k_scatter       <<<NB, 256, 0, stream>>>(p2buf, sel_count, sel_list, scores);
  k_softmax       <<<NB, 256, 0, stream>>>(scores, mask, attn);
  k_ctx_partial   <<<256, 256, 0, stream>>>(attn, xs, cp);
  k_ctx_reduce    <<<128, 256, 0, stream>>>(cp, ctx);
}